// Round 2
// baseline (865.233 us; speedup 1.0000x reference)
//
#include <hip/hip_runtime.h>
#include <hip/hip_bf16.h>
#include <math.h>
#include <stdint.h>

// ---- problem constants ----
#define BATCH 8192
#define NCLUST 4096
#define DIM 3072

typedef __bf16 bf16;
typedef __bf16 bf16x4 __attribute__((ext_vector_type(4)));
typedef __bf16 bf16x8 __attribute__((ext_vector_type(8)));
typedef float f32x4 __attribute__((ext_vector_type(4)));
typedef int i32x4 __attribute__((ext_vector_type(4)));

__device__ __forceinline__ void get_scalars(const float* t, const float* sdv,
                                            float& scale, float& vt, float& dw) {
    float s = expf(-t[0]);
    float sd = sdv[0];
    float s2sd2 = s * s * sd * sd;
    float var = 1.0f - s * s;
    scale = s;
    vt = s2sd2 + var;
    dw = s2sd2 / vt;
}

// async global->LDS, 16 bytes per lane. LDS dest is wave-uniform base + lane*16
// (hardware constraint); per-lane GLOBAL address carries the swizzle.
__device__ __forceinline__ void async16(const bf16* g, bf16* l) {
    __builtin_amdgcn_global_load_lds(
        (const __attribute__((address_space(1))) void*)g,
        (__attribute__((address_space(3))) void*)l, 16, 0, 0);
}

// ---------------- prep kernels ----------------

// x fp32 -> bf16 (4 elems/thread)
__global__ __launch_bounds__(256) void cvt_x_kernel(const float* __restrict__ x,
                                                    bf16* __restrict__ xb, int n4) {
    int i = blockIdx.x * blockDim.x + threadIdx.x;
    if (i >= n4) return;
    float4 v = ((const float4*)x)[i];
    bf16x4 o = {(bf16)v.x, (bf16)v.y, (bf16)v.z, (bf16)v.w};
    ((bf16x4*)xb)[i] = o;
}

// per-cluster: sc = means*scale (bf16, row-major [N,D]) and c_sq = ||sc||^2
__global__ __launch_bounds__(256) void prep_sc_kernel(const float* __restrict__ means,
                                                      const float* __restrict__ t,
                                                      bf16* __restrict__ scb,
                                                      float* __restrict__ c_sq) {
    __shared__ float red[4];
    int row = blockIdx.x, tid = threadIdx.x;
    float scale = expf(-t[0]);
    const float4* m4 = (const float4*)(means + (size_t)row * DIM);
    bf16x4* o4 = (bf16x4*)(scb + (size_t)row * DIM);
    float s = 0.f;
#pragma unroll
    for (int j = 0; j < 3; ++j) {  // 3072 = 256*4*3
        float4 v = m4[tid + 256 * j];
        float a = v.x * scale, b = v.y * scale, c = v.z * scale, d = v.w * scale;
        s += a * a + b * b + c * c + d * d;
        bf16x4 o = {(bf16)a, (bf16)b, (bf16)c, (bf16)d};
        o4[tid + 256 * j] = o;
    }
    for (int off = 32; off > 0; off >>= 1) s += __shfl_down(s, off);
    if ((tid & 63) == 0) red[tid >> 6] = s;
    __syncthreads();
    if (tid == 0) c_sq[row] = red[0] + red[1] + red[2] + red[3];
}

// scT[d][n] = means[n][d]*scale (bf16, [DIM, NCLUST]) via LDS tile
__global__ __launch_bounds__(256) void transpose_sc_kernel(const float* __restrict__ means,
                                                           const float* __restrict__ t,
                                                           bf16* __restrict__ scT) {
    __shared__ bf16 tile[64][65];
    float scale = expf(-t[0]);
    int tid = threadIdx.x;
    int tx = tid & 63, ty = tid >> 6;
    int d0 = blockIdx.x * 64, n0 = blockIdx.y * 64;
#pragma unroll
    for (int i = 0; i < 16; ++i) {
        int nr = ty + 4 * i;
        tile[nr][tx] = (bf16)(means[(size_t)(n0 + nr) * DIM + d0 + tx] * scale);
    }
    __syncthreads();
#pragma unroll
    for (int i = 0; i < 16; ++i) {
        int dr = ty + 4 * i;
        scT[(size_t)(d0 + dr) * NCLUST + n0 + tx] = tile[tx][dr];
    }
}

// ---------------- GEMM (C = A * B^T), 128x128x32 ----------------
// Staging transport: __builtin_amdgcn_global_load_lds width=16 (m97 structure;
// m151 A/B: reg-staged 646 TF vs gload_lds 874 TF at this exact tile). The LDS
// XOR swizzle is PRESERVED: gload_lds writes LDS linearly (wave base +
// lane*16), the swizzle lives on the per-lane GLOBAL source address
// (skc0/skc1), and the reader applies the same involution (swq) -- the
// rule-#21 "linear dest + inverse-swizzled source + swizzled read" form.
// One __syncthreads per iter; its implicit vmcnt(0) drain lands after the
// MFMAs so prefetch of tile k+1 overlaps compute of tile k.
// epi==1: C[m][n] = (acc - 0.5*c_sq[n]) / vt         (logits, fp32, stride N)
// epi==2: C[m][n] = (dw*x[m][n] + (1-dw)*acc)/scale  (output,  fp32, stride N)

__device__ __forceinline__ void compute_tile(const bf16* asb, const bf16* bsb,
                                             f32x4 acc[4][4], int wr, int wc,
                                             int lrow, int swq) {
    bf16x8 av[4], bv[4];
#pragma unroll
    for (int ti = 0; ti < 4; ++ti)
        av[ti] = *(const bf16x8*)(asb + (wr * 64 + ti * 16 + lrow) * 32 + swq * 8);
#pragma unroll
    for (int tj = 0; tj < 4; ++tj)
        bv[tj] = *(const bf16x8*)(bsb + (wc * 64 + tj * 16 + lrow) * 32 + swq * 8);
#pragma unroll
    for (int ti = 0; ti < 4; ++ti)
#pragma unroll
        for (int tj = 0; tj < 4; ++tj)
            acc[ti][tj] = __builtin_amdgcn_mfma_f32_16x16x32_bf16(
                av[ti], bv[tj], acc[ti][tj], 0, 0, 0);
}

__global__ __launch_bounds__(256) void gemm_bt_kernel(
    const bf16* __restrict__ A, const bf16* __restrict__ B,
    int M, int N, int K, int lda,
    const float* __restrict__ t, const float* __restrict__ sdv,
    const float* __restrict__ c_sq, const float* __restrict__ xres,
    float* __restrict__ C, int epi) {
    __shared__ __attribute__((aligned(16))) bf16 As[2][128 * 32];
    __shared__ __attribute__((aligned(16))) bf16 Bs[2][128 * 32];

    const int tid = threadIdx.x;
    const int lane = tid & 63;
    const int w = tid >> 6;             // wave 0..3
    const int wr = w >> 1, wc = w & 1;  // 2x2 wave grid, each wave 64x64
    const int lrow = lane & 15;         // m/n within 16
    const int lq = lane >> 4;           // k-quad
    const int swq = lq ^ ((lrow >> 1) & 3);  // swizzled chunk position to read
    const int m0 = blockIdx.y * 128, n0 = blockIdx.x * 128;

    // staging indices (swizzled global chunk per linear LDS slot)
    const int c0 = tid;            // LDS chunk index, first slot
    const int c1 = tid + 256;      // second slot
    const int srow0 = c0 >> 2, skc0 = (c0 & 3) ^ ((srow0 >> 1) & 3);
    const int srow1 = c1 >> 2, skc1 = (c1 & 3) ^ ((srow1 >> 1) & 3);

    const bf16* gA0 = A + (size_t)(m0 + srow0) * lda + skc0 * 8;
    const bf16* gA1 = A + (size_t)(m0 + srow1) * lda + skc1 * 8;
    const bf16* gB0 = B + (size_t)(n0 + srow0) * K + skc0 * 8;
    const bf16* gB1 = B + (size_t)(n0 + srow1) * K + skc1 * 8;

    f32x4 acc[4][4];
#pragma unroll
    for (int i = 0; i < 4; ++i)
#pragma unroll
        for (int j = 0; j < 4; ++j) acc[i][j] = f32x4{0.f, 0.f, 0.f, 0.f};

    // prologue: stage tile 0 (async direct-to-LDS; syncthreads drains vmcnt)
    async16(gA0, &As[0][c0 * 8]);
    async16(gA1, &As[0][c1 * 8]);
    async16(gB0, &Bs[0][c0 * 8]);
    async16(gB1, &Bs[0][c1 * 8]);
    __syncthreads();

    const int nk = K >> 5;
    int buf = 0;
    for (int it = 0; it < nk - 1; ++it) {
        const int off = (it + 1) << 5;
        // issue async prefetch of tile it+1 into the alternate buffer; the
        // MFMAs below overlap the in-flight loads, the barrier's vmcnt(0)
        // drain lands after compute.
        bf16* asn = &As[buf ^ 1][0];
        bf16* bsn = &Bs[buf ^ 1][0];
        async16(gA0 + off, asn + c0 * 8);
        async16(gA1 + off, asn + c1 * 8);
        async16(gB0 + off, bsn + c0 * 8);
        async16(gB1 + off, bsn + c1 * 8);

        compute_tile(&As[buf][0], &Bs[buf][0], acc, wr, wc, lrow, swq);

        __syncthreads();
        buf ^= 1;
    }
    compute_tile(&As[buf][0], &Bs[buf][0], acc, wr, wc, lrow, swq);

    float scale, vt, dw;
    get_scalars(t, sdv, scale, vt, dw);

    if (epi == 1) {
        const float inv_vt = 1.0f / vt;
#pragma unroll
        for (int ti = 0; ti < 4; ++ti) {
            int rbase = m0 + wr * 64 + ti * 16 + lq * 4;
#pragma unroll
            for (int tj = 0; tj < 4; ++tj) {
                int col = n0 + wc * 64 + tj * 16 + lrow;
                float csq = c_sq[col];
#pragma unroll
                for (int r = 0; r < 4; ++r)
                    __builtin_nontemporal_store(
                        (acc[ti][tj][r] - 0.5f * csq) * inv_vt,
                        &C[(size_t)(rbase + r) * N + col]);
            }
        }
    } else {
        const float inv_scale = 1.0f / scale;
        const float wx = dw * inv_scale;
        const float wcl = (1.0f - dw) * inv_scale;
#pragma unroll
        for (int ti = 0; ti < 4; ++ti) {
            int rbase = m0 + wr * 64 + ti * 16 + lq * 4;
#pragma unroll
            for (int tj = 0; tj < 4; ++tj) {
                int col = n0 + wc * 64 + tj * 16 + lrow;
#pragma unroll
                for (int r = 0; r < 4; ++r) {
                    size_t idx = (size_t)(rbase + r) * N + col;
                    float xv = __builtin_nontemporal_load(&xres[idx]);
                    __builtin_nontemporal_store(wx * xv + wcl * acc[ti][tj][r],
                                                &C[idx]);
                }
            }
        }
    }
}

// ---------------- softmax over rows of S [BATCH, NCLUST] ----------------
// in-place: reads fp32 row, writes bf16 P into the first half of the same row.
__global__ __launch_bounds__(256) void softmax_kernel(float* __restrict__ S) {
    __shared__ float red[4];
    int b = blockIdx.x, tid = threadIdx.x;
    int lane = tid & 63;
    float* srow = S + (size_t)b * NCLUST;
    const f32x4* s4 = (const f32x4*)srow;
    f32x4 v[4];
#pragma unroll
    for (int j = 0; j < 4; ++j) v[j] = __builtin_nontemporal_load(&s4[tid + 256 * j]);

    float mx = -3.4e38f;
#pragma unroll
    for (int j = 0; j < 4; ++j)
        mx = fmaxf(mx, fmaxf(fmaxf(v[j][0], v[j][1]), fmaxf(v[j][2], v[j][3])));
    for (int off = 32; off > 0; off >>= 1) mx = fmaxf(mx, __shfl_down(mx, off));
    if (lane == 0) red[tid >> 6] = mx;
    __syncthreads();
    mx = fmaxf(fmaxf(red[0], red[1]), fmaxf(red[2], red[3]));
    __syncthreads();  // before red reuse

    float e[16];
    float s = 0.f;
#pragma unroll
    for (int j = 0; j < 4; ++j) {
#pragma unroll
        for (int q = 0; q < 4; ++q) {
            e[4 * j + q] = expf(v[j][q] - mx);
            s += e[4 * j + q];
        }
    }
    for (int off = 32; off > 0; off >>= 1) s += __shfl_down(s, off);
    if (lane == 0) red[tid >> 6] = s;
    __syncthreads();
    s = red[0] + red[1] + red[2] + red[3];
    float inv = 1.0f / s;

    // all reads completed before the barriers above; safe to overwrite in place
    bf16x4* p4 = (bf16x4*)srow;  // row stride becomes 2*NCLUST bf16 elems
#pragma unroll
    for (int j = 0; j < 4; ++j) {
        bf16x4 o = {(bf16)(e[4 * j + 0] * inv), (bf16)(e[4 * j + 1] * inv),
                    (bf16)(e[4 * j + 2] * inv), (bf16)(e[4 * j + 3] * inv)};
        p4[tid + 256 * j] = o;
    }
}

// ---------------- launch ----------------
extern "C" void kernel_launch(void* const* d_in, const int* in_sizes, int n_in,
                              void* d_out, int out_size, void* d_ws, size_t ws_size,
                              hipStream_t stream) {
    const float* x = (const float*)d_in[0];      // [8192,3,32,32]
    const float* t = (const float*)d_in[1];      // [1]
    const float* means = (const float*)d_in[2];  // [4096,3,32,32]
    const float* sdv = (const float*)d_in[3];    // [1]
    float* out = (float*)d_out;

    // workspace layout (total ~224 MB)
    char* ws = (char*)d_ws;
    bf16* xb = (bf16*)ws;                              // 8192*3072*2 = 50331648
    bf16* scb = (bf16*)(ws + 50331648);                // 4096*3072*2 = 25165824
    bf16* scT = (bf16*)(ws + 75497472);                // 3072*4096*2 = 25165824
    float* c_sq = (float*)(ws + 100663296);            // 4096*4
    float* S = (float*)(ws + 100679680);               // 8192*4096*4 = 134217728
    // P (bf16) is written in-place over S: row b at (bf16*)S + b*8192

    cvt_x_kernel<<<(BATCH * DIM / 4 + 255) / 256, 256, 0, stream>>>(x, xb, BATCH * DIM / 4);
    prep_sc_kernel<<<NCLUST, 256, 0, stream>>>(means, t, scb, c_sq);
    transpose_sc_kernel<<<dim3(DIM / 64, NCLUST / 64), 256, 0, stream>>>(means, t, scT);

    // GEMM1: S[b][n] = (xb . scb_n - 0.5*c_sq[n]) / vt
    gemm_bt_kernel<<<dim3(NCLUST / 128, BATCH / 128), 256, 0, stream>>>(
        xb, scb, BATCH, NCLUST, DIM, DIM, t, sdv, c_sq, nullptr, S, 1);

    softmax_kernel<<<BATCH, 256, 0, stream>>>(S);

    // GEMM2: out[b][d] = (dw*x + (1-dw)*(P . scT_d)) / scale ; P rows stride 8192
    gemm_bt_kernel<<<dim3(DIM / 128, BATCH / 128), 256, 0, stream>>>(
        (const bf16*)S, scT, BATCH, DIM, NCLUST, 2 * NCLUST, t, sdv, nullptr, x, out, 2);
}

// Round 3
// 707.374 us; speedup vs baseline: 1.2232x; 1.2232x over previous
//
#include <hip/hip_runtime.h>
#include <hip/hip_bf16.h>
#include <math.h>
#include <stdint.h>

// ---- problem constants ----
#define BATCH 8192
#define NCLUST 4096
#define DIM 3072

typedef __bf16 bf16;
typedef __bf16 bf16x4 __attribute__((ext_vector_type(4)));
typedef __bf16 bf16x8 __attribute__((ext_vector_type(8)));
typedef float f32x4 __attribute__((ext_vector_type(4)));

__device__ __forceinline__ void get_scalars(const float* t, const float* sdv,
                                            float& scale, float& vt, float& dw) {
    float s = expf(-t[0]);
    float sd = sdv[0];
    float s2sd2 = s * s * sd * sd;
    float var = 1.0f - s * s;
    scale = s;
    vt = s2sd2 + var;
    dw = s2sd2 / vt;
}

// async global->LDS, 16 bytes per lane. LDS dest is wave-uniform base + lane*16
// (hardware constraint); per-lane GLOBAL address carries the swizzle.
__device__ __forceinline__ void async16(const bf16* g, bf16* l) {
    __builtin_amdgcn_global_load_lds(
        (const __attribute__((address_space(1))) void*)g,
        (__attribute__((address_space(3))) void*)l, 16, 0, 0);
}

// ---------------- prep kernels ----------------

__global__ __launch_bounds__(256) void cvt_x_kernel(const float* __restrict__ x,
                                                    bf16* __restrict__ xb, int n4) {
    int i = blockIdx.x * blockDim.x + threadIdx.x;
    if (i >= n4) return;
    float4 v = ((const float4*)x)[i];
    bf16x4 o = {(bf16)v.x, (bf16)v.y, (bf16)v.z, (bf16)v.w};
    ((bf16x4*)xb)[i] = o;
}

__global__ __launch_bounds__(256) void prep_sc_kernel(const float* __restrict__ means,
                                                      const float* __restrict__ t,
                                                      bf16* __restrict__ scb,
                                                      float* __restrict__ c_sq) {
    __shared__ float red[4];
    int row = blockIdx.x, tid = threadIdx.x;
    float scale = expf(-t[0]);
    const float4* m4 = (const float4*)(means + (size_t)row * DIM);
    bf16x4* o4 = (bf16x4*)(scb + (size_t)row * DIM);
    float s = 0.f;
#pragma unroll
    for (int j = 0; j < 3; ++j) {  // 3072 = 256*4*3
        float4 v = m4[tid + 256 * j];
        float a = v.x * scale, b = v.y * scale, c = v.z * scale, d = v.w * scale;
        s += a * a + b * b + c * c + d * d;
        bf16x4 o = {(bf16)a, (bf16)b, (bf16)c, (bf16)d};
        o4[tid + 256 * j] = o;
    }
    for (int off = 32; off > 0; off >>= 1) s += __shfl_down(s, off);
    if ((tid & 63) == 0) red[tid >> 6] = s;
    __syncthreads();
    if (tid == 0) c_sq[row] = red[0] + red[1] + red[2] + red[3];
}

__global__ __launch_bounds__(256) void transpose_sc_kernel(const float* __restrict__ means,
                                                           const float* __restrict__ t,
                                                           bf16* __restrict__ scT) {
    __shared__ bf16 tile[64][65];
    float scale = expf(-t[0]);
    int tid = threadIdx.x;
    int tx = tid & 63, ty = tid >> 6;
    int d0 = blockIdx.x * 64, n0 = blockIdx.y * 64;
#pragma unroll
    for (int i = 0; i < 16; ++i) {
        int nr = ty + 4 * i;
        tile[nr][tx] = (bf16)(means[(size_t)(n0 + nr) * DIM + d0 + tx] * scale);
    }
    __syncthreads();
#pragma unroll
    for (int i = 0; i < 16; ++i) {
        int dr = ty + 4 * i;
        scT[(size_t)(d0 + dr) * NCLUST + n0 + tx] = tile[tx][dr];
    }
}

// ---------------- GEMM (C = A * B^T), 256x256x64, 8-wave 8-phase ----------------
// T3+T4+T2+T5 template (m201 structure, 1563-1728 TF verified on 4k/8k GEMM):
//  - 512 threads = 8 waves in a 2(M) x 4(N) grid; per-wave output 128x64.
//  - LDS = 2 bufs x 2 halves x [128 rows x 64 cols] bf16 for each of A,B = 128 KiB.
//  - Per K-tile (BK=64), 4 phases. Phase = {ds_reads; issue one half-tile of
//    global_load_lds prefetch; s_barrier; lgkmcnt(0); setprio(1); 16 MFMA;
//    setprio(0); s_barrier}.
//  - Counted vmcnt(4) ONCE per K-tile (end of P4): retires exactly the next
//    tile's 4 half-tiles (8 loads), leaves 2 half-tiles in flight. Never
//    vmcnt(0) in steady state; vmcnt(0) only at tile NT-2 (tail).
//  - Slot recycling: A-slot last ds_read at P3 -> restaged at P4 (for t+2);
//    B-slot last read at P2 -> restaged at P3; other buffer's B-high/A-high
//    restaged at P1/P2 (for t+1). Issue->consume distance 4-7 phases.
//  - Swizzle (rule #21): LDS linear dest; global source chunk = pos^(row&7);
//    ds_read chunk pos = (kh*4+lq)^(lrow&7) -> 2 lanes/bank (free, m136).
// Requires NT = K/64 >= 3 (here 48 and 64).
// epi==1: C[m][n] = (acc - 0.5*c_sq[n]) / vt         (logits, fp32, stride N)
// epi==2: C[m][n] = (dw*x[m][n] + (1-dw)*acc)/scale  (output,  fp32, stride N)

__device__ __forceinline__ void stage2(const bf16* g, size_t ld64, bf16* lds,
                                       int koff, int tid) {
    async16(g + koff, lds + tid * 8);
    async16(g + koff + ld64, lds + (tid + 512) * 8);
}

__global__ __launch_bounds__(512, 2) void gemm256_kernel(
    const bf16* __restrict__ A, const bf16* __restrict__ B,
    int M, int N, int K, int lda,
    const float* __restrict__ t, const float* __restrict__ sdv,
    const float* __restrict__ c_sq, const float* __restrict__ xres,
    float* __restrict__ C, int epi) {
    __shared__ __attribute__((aligned(16))) bf16 As[2][2][128 * 64];
    __shared__ __attribute__((aligned(16))) bf16 Bs[2][2][128 * 64];

    const int tid = threadIdx.x;
    const int lane = tid & 63;
    const int wid = tid >> 6;
    const int wr = wid >> 2;  // 0..1: M half
    const int wc = wid & 3;   // 0..3: N quarter
    const int lrow = lane & 15;
    const int lq = lane >> 4;
    const int m0 = blockIdx.y * 256, n0 = blockIdx.x * 256;

    // staging: thread owns chunks {tid, tid+512} of each 128x64 half-tile.
    // LDS pos = chunk index (linear); global chunk = (pos)^(row&7).
    const int srow = tid >> 3;               // 0..63
    const int sgc = (tid & 7) ^ (srow & 7);  // swizzled global k-chunk
    const bf16* gA0 = A + (size_t)(m0 + srow) * lda + sgc * 8;
    const bf16* gA1 = gA0 + (size_t)128 * lda;
    const bf16* gB0 = B + (size_t)(n0 + srow) * K + sgc * 8;
    const bf16* gB1 = gB0 + (size_t)128 * K;
    const size_t a64 = (size_t)64 * lda;
    const size_t b64 = (size_t)64 * K;

    // reader offsets (elements) within one [128][64] half, swizzled chunk pos
    const int x7 = lrow & 7;
    const int pos0 = lq ^ x7;        // kh=0
    const int pos1 = (4 + lq) ^ x7;  // kh=1
    const int aoff0 = lrow * 64 + pos0 * 8;
    const int aoff1 = lrow * 64 + pos1 * 8;
    const int brbase = (wc & 1) * 64 + lrow;
    const int boff0 = brbase * 64 + pos0 * 8;
    const int boff1 = brbase * 64 + pos1 * 8;

    f32x4 acc[8][4];
#pragma unroll
    for (int i = 0; i < 8; ++i)
#pragma unroll
        for (int j = 0; j < 4; ++j) acc[i][j] = f32x4{0.f, 0.f, 0.f, 0.f};

    const int NT = K >> 6;  // >= 3 required

    // prologue: tile0 complete + B-low(1) + A-low(1); wait tile0 (oldest 8)
    stage2(gA0, a64, &As[0][0][0], 0, tid);
    stage2(gA1, a64, &As[0][1][0], 0, tid);
    stage2(gB0, b64, &Bs[0][0][0], 0, tid);
    stage2(gB1, b64, &Bs[0][1][0], 0, tid);
    stage2(gB0, b64, &Bs[1][0][0], 64, tid);
    stage2(gA0, a64, &As[1][0][0], 64, tid);
    asm volatile("s_waitcnt vmcnt(4)" ::: "memory");
    __builtin_amdgcn_s_barrier();

    for (int tt = 0; tt < NT; ++tt) {
        const int buf = tt & 1;
        const bf16* Aw = &As[buf][wr][0];
        const bf16* Bw = &Bs[buf][wc >> 1][0];
        bf16x8 a_[4][2], bA[2][2], bB[2][2];

        // ---------- P1: read A m0-3 (8) + B n0-1 (4); stage B-high(t+1) ----------
#pragma unroll
        for (int i = 0; i < 4; ++i) {
            a_[i][0] = *(const bf16x8*)(Aw + i * 1024 + aoff0);
            a_[i][1] = *(const bf16x8*)(Aw + i * 1024 + aoff1);
        }
#pragma unroll
        for (int j = 0; j < 2; ++j) {
            bA[j][0] = *(const bf16x8*)(Bw + j * 1024 + boff0);
            bA[j][1] = *(const bf16x8*)(Bw + j * 1024 + boff1);
        }
        if (tt + 1 < NT) stage2(gB1, b64, &Bs[buf ^ 1][1][0], (tt + 1) << 6, tid);
        __builtin_amdgcn_s_barrier();
        asm volatile("s_waitcnt lgkmcnt(0)" ::: "memory");
        __builtin_amdgcn_s_setprio(1);
#pragma unroll
        for (int i = 0; i < 4; ++i)
#pragma unroll
            for (int j = 0; j < 2; ++j) {
                acc[i][j] = __builtin_amdgcn_mfma_f32_16x16x32_bf16(a_[i][0], bA[j][0], acc[i][j], 0, 0, 0);
                acc[i][j] = __builtin_amdgcn_mfma_f32_16x16x32_bf16(a_[i][1], bA[j][1], acc[i][j], 0, 0, 0);
            }
        __builtin_amdgcn_s_setprio(0);
        __builtin_amdgcn_s_barrier();

        // ---------- P2: read B n2-3 (4); stage A-high(t+1) ----------
#pragma unroll
        for (int j = 0; j < 2; ++j) {
            bB[j][0] = *(const bf16x8*)(Bw + (2 + j) * 1024 + boff0);
            bB[j][1] = *(const bf16x8*)(Bw + (2 + j) * 1024 + boff1);
        }
        if (tt + 1 < NT) stage2(gA1, a64, &As[buf ^ 1][1][0], (tt + 1) << 6, tid);
        __builtin_amdgcn_s_barrier();
        asm volatile("s_waitcnt lgkmcnt(0)" ::: "memory");
        __builtin_amdgcn_s_setprio(1);
#pragma unroll
        for (int i = 0; i < 4; ++i)
#pragma unroll
            for (int j = 0; j < 2; ++j) {
                acc[i][2 + j] = __builtin_amdgcn_mfma_f32_16x16x32_bf16(a_[i][0], bB[j][0], acc[i][2 + j], 0, 0, 0);
                acc[i][2 + j] = __builtin_amdgcn_mfma_f32_16x16x32_bf16(a_[i][1], bB[j][1], acc[i][2 + j], 0, 0, 0);
            }
        __builtin_amdgcn_s_setprio(0);
        __builtin_amdgcn_s_barrier();

        // ---------- P3: read A m4-7 (8, reuse regs); stage B-low(t+2) ----------
#pragma unroll
        for (int i = 0; i < 4; ++i) {
            a_[i][0] = *(const bf16x8*)(Aw + (4 + i) * 1024 + aoff0);
            a_[i][1] = *(const bf16x8*)(Aw + (4 + i) * 1024 + aoff1);
        }
        if (tt + 2 < NT) stage2(gB0, b64, &Bs[buf][0][0], (tt + 2) << 6, tid);
        __builtin_amdgcn_s_barrier();
        asm volatile("s_waitcnt lgkmcnt(0)" ::: "memory");
        __builtin_amdgcn_s_setprio(1);
#pragma unroll
        for (int i = 0; i < 4; ++i)
#pragma unroll
            for (int j = 0; j < 2; ++j) {
                acc[4 + i][2 + j] = __builtin_amdgcn_mfma_f32_16x16x32_bf16(a_[i][0], bB[j][0], acc[4 + i][2 + j], 0, 0, 0);
                acc[4 + i][2 + j] = __builtin_amdgcn_mfma_f32_16x16x32_bf16(a_[i][1], bB[j][1], acc[4 + i][2 + j], 0, 0, 0);
            }
        __builtin_amdgcn_s_setprio(0);
        __builtin_amdgcn_s_barrier();

        // ---------- P4: stage A-low(t+2); MFMA m4-7 x n0-1; counted vmcnt ----------
        if (tt + 2 < NT) stage2(gA0, a64, &As[buf][0][0], (tt + 2) << 6, tid);
        __builtin_amdgcn_s_barrier();
        __builtin_amdgcn_s_setprio(1);
#pragma unroll
        for (int i = 0; i < 4; ++i)
#pragma unroll
            for (int j = 0; j < 2; ++j) {
                acc[4 + i][j] = __builtin_amdgcn_mfma_f32_16x16x32_bf16(a_[i][0], bA[j][0], acc[4 + i][j], 0, 0, 0);
                acc[4 + i][j] = __builtin_amdgcn_mfma_f32_16x16x32_bf16(a_[i][1], bA[j][1], acc[4 + i][j], 0, 0, 0);
            }
        __builtin_amdgcn_s_setprio(0);
        if (tt < NT - 2) {
            asm volatile("s_waitcnt vmcnt(4)" ::: "memory");  // next tile landed
        } else if (tt == NT - 2) {
            asm volatile("s_waitcnt vmcnt(0)" ::: "memory");  // tail drain
        }
        __builtin_amdgcn_s_barrier();
    }

    float scale, vt, dw;
    get_scalars(t, sdv, scale, vt, dw);

    if (epi == 1) {
        const float inv_vt = 1.0f / vt;
#pragma unroll
        for (int m = 0; m < 8; ++m) {
            int rbase = m0 + wr * 128 + m * 16 + lq * 4;
#pragma unroll
            for (int n = 0; n < 4; ++n) {
                int col = n0 + wc * 64 + n * 16 + lrow;
                float csq = c_sq[col];
#pragma unroll
                for (int r = 0; r < 4; ++r)
                    __builtin_nontemporal_store(
                        (acc[m][n][r] - 0.5f * csq) * inv_vt,
                        &C[(size_t)(rbase + r) * N + col]);
            }
        }
    } else {
        const float inv_scale = 1.0f / scale;
        const float wx = dw * inv_scale;
        const float wcl = (1.0f - dw) * inv_scale;
#pragma unroll
        for (int m = 0; m < 8; ++m) {
            int rbase = m0 + wr * 128 + m * 16 + lq * 4;
#pragma unroll
            for (int n = 0; n < 4; ++n) {
                int col = n0 + wc * 64 + n * 16 + lrow;
#pragma unroll
                for (int r = 0; r < 4; ++r) {
                    size_t idx = (size_t)(rbase + r) * N + col;
                    float xv = __builtin_nontemporal_load(&xres[idx]);
                    __builtin_nontemporal_store(wx * xv + wcl * acc[m][n][r],
                                                &C[idx]);
                }
            }
        }
    }
}

// ---------------- softmax over rows of S [BATCH, NCLUST] ----------------
// in-place: reads fp32 row, writes bf16 P into the first half of the same row.
__global__ __launch_bounds__(256) void softmax_kernel(float* __restrict__ S) {
    __shared__ float red[4];
    int b = blockIdx.x, tid = threadIdx.x;
    int lane = tid & 63;
    float* srow = S + (size_t)b * NCLUST;
    const f32x4* s4 = (const f32x4*)srow;
    f32x4 v[4];
#pragma unroll
    for (int j = 0; j < 4; ++j) v[j] = __builtin_nontemporal_load(&s4[tid + 256 * j]);

    float mx = -3.4e38f;
#pragma unroll
    for (int j = 0; j < 4; ++j)
        mx = fmaxf(mx, fmaxf(fmaxf(v[j][0], v[j][1]), fmaxf(v[j][2], v[j][3])));
    for (int off = 32; off > 0; off >>= 1) mx = fmaxf(mx, __shfl_down(mx, off));
    if (lane == 0) red[tid >> 6] = mx;
    __syncthreads();
    mx = fmaxf(fmaxf(red[0], red[1]), fmaxf(red[2], red[3]));
    __syncthreads();  // before red reuse

    float e[16];
    float s = 0.f;
#pragma unroll
    for (int j = 0; j < 4; ++j) {
#pragma unroll
        for (int q = 0; q < 4; ++q) {
            e[4 * j + q] = expf(v[j][q] - mx);
            s += e[4 * j + q];
        }
    }
    for (int off = 32; off > 0; off >>= 1) s += __shfl_down(s, off);
    if (lane == 0) red[tid >> 6] = s;
    __syncthreads();
    s = red[0] + red[1] + red[2] + red[3];
    float inv = 1.0f / s;

    bf16x4* p4 = (bf16x4*)srow;  // row stride becomes 2*NCLUST bf16 elems
#pragma unroll
    for (int j = 0; j < 4; ++j) {
        bf16x4 o = {(bf16)(e[4 * j + 0] * inv), (bf16)(e[4 * j + 1] * inv),
                    (bf16)(e[4 * j + 2] * inv), (bf16)(e[4 * j + 3] * inv)};
        p4[tid + 256 * j] = o;
    }
}

// ---------------- launch ----------------
extern "C" void kernel_launch(void* const* d_in, const int* in_sizes, int n_in,
                              void* d_out, int out_size, void* d_ws, size_t ws_size,
                              hipStream_t stream) {
    const float* x = (const float*)d_in[0];      // [8192,3,32,32]
    const float* t = (const float*)d_in[1];      // [1]
    const float* means = (const float*)d_in[2];  // [4096,3,32,32]
    const float* sdv = (const float*)d_in[3];    // [1]
    float* out = (float*)d_out;

    // workspace layout (total ~224 MB)
    char* ws = (char*)d_ws;
    bf16* xb = (bf16*)ws;                              // 8192*3072*2 = 50331648
    bf16* scb = (bf16*)(ws + 50331648);                // 4096*3072*2 = 25165824
    bf16* scT = (bf16*)(ws + 75497472);                // 3072*4096*2 = 25165824
    float* c_sq = (float*)(ws + 100663296);            // 4096*4
    float* S = (float*)(ws + 100679680);               // 8192*4096*4 = 134217728
    // P (bf16) is written in-place over S: row b at (bf16*)S + b*8192

    cvt_x_kernel<<<(BATCH * DIM / 4 + 255) / 256, 256, 0, stream>>>(x, xb, BATCH * DIM / 4);
    prep_sc_kernel<<<NCLUST, 256, 0, stream>>>(means, t, scb, c_sq);
    transpose_sc_kernel<<<dim3(DIM / 64, NCLUST / 64), 256, 0, stream>>>(means, t, scT);

    // GEMM1: S[b][n] = (xb . scb_n - 0.5*c_sq[n]) / vt
    gemm256_kernel<<<dim3(NCLUST / 256, BATCH / 256), 512, 0, stream>>>(
        xb, scb, BATCH, NCLUST, DIM, DIM, t, sdv, c_sq, nullptr, S, 1);

    softmax_kernel<<<BATCH, 256, 0, stream>>>(S);

    // GEMM2: out[b][d] = (dw*x + (1-dw)*(P . scT_d)) / scale ; P rows stride 8192
    gemm256_kernel<<<dim3(DIM / 256, BATCH / 256), 512, 0, stream>>>(
        (const bf16*)S, scT, BATCH, DIM, NCLUST, 2 * NCLUST, t, sdv, nullptr, x, out, 2);
}